// Round 17
// baseline (56.253 us; speedup 1.0000x reference)
//
#include <hip/hip_runtime.h>

// Problem constants (from reference setup_inputs)
#define Bn 256
#define En 8
#define Vn 32000
#define Ln 128
#define BEn (Bn * En)        // 2048
#define END_TOK 2
#define NV4 (Vn / 4)         // 8000 float4 strips per segment
#define NCH 125              // 1KB chunks per segment (64 strips each)
#define CHALF 63             // first-half chunk count (h=0: [0,63), h=1: [63,125))
#define CAPW 128             // survivor-list capacity per segment (mean 43, sd 6.6)

// d_out layout (all values stored as float32, outputs concatenated in return order)
#define OFF_CUR   0                          // cur_input  [B*E]
#define OFF_TOPP  (BEn)                      // top_p      [B,E]
#define OFF_OUTS  (2 * BEn)                  // outs_new   [L+1,B,E]
#define OFF_ENDED (2 * BEn + (Ln + 1) * BEn) // ended_new  [B,E]
#define OFF_BEAM  (3 * BEn + (Ln + 1) * BEn) // topk_beam  [B,E]

#define NEG_INF (-__builtin_inff())
#define IDX_SENTINEL 0x7fffffff

// Filter threshold on RAW cp values (pr segment-constant + fp-add monotone
// => raw-order filter selects exactly the sum-order top-8 candidates).
// 8th order stat of 32000 N(0,1) ~ 3.55; P(count<8 | t=3.0) ~ 1e-9;
// P(count>128) ~ 1e-25. Both fall back to an exact rescan.
#define THRESH 3.0f

typedef __attribute__((ext_vector_type(4))) float f32x4;

__device__ __forceinline__ float4 ld_sel(const float4* p, bool prot) {
    if (prot) return *p;
    f32x4 t = __builtin_nontemporal_load((const f32x4*)p);
    union { f32x4 a; float4 b; } u; u.a = t; return u.b;
}

// Butterfly arg-max over 64 lanes under total order (val desc, idx asc).
__device__ __forceinline__ void wave_argmax(float& v, int& ix, int& ln) {
#pragma unroll
    for (int off = 32; off > 0; off >>= 1) {
        float v2 = __shfl_xor(v, off, 64);
        int   i2 = __shfl_xor(ix, off, 64);
        int   l2 = __shfl_xor(ln, off, 64);
        bool take = (v2 > v) || (v2 == v && i2 < ix);
        v  = take ? v2 : v;
        ix = take ? i2 : ix;
        ln = take ? l2 : ln;
    }
}

// Single fused kernel: one block per b, 16 waves (1024 threads).
// Wave w streams half (w&1) of segment w>>1 (63-64 KB sequential per wave).
// The history row outs[:, b, :] (4 KB) is prefetched into registers at
// kernel entry (latency hides under the stream) and parked in LDS, so the
// post-stream tail has no cold global round-trip. Survivor lists ->
// per-wave exact top-8 -> block merge (reference order) -> scalars + gather.
__global__ __launch_bounds__(1024) void k_beam_add(
        const float* __restrict__ cp, const float* __restrict__ proba,
        const int* __restrict__ ended, const int* __restrict__ outs,
        float* __restrict__ dout) {
    const int b    = blockIdx.x;
    const int tid  = threadIdx.x;
    const int w    = tid >> 6;       // wave 0..15
    const int lane = tid & 63;

    __shared__ int   s_cnt[8];
    __shared__ float s_cv[8][CAPW];
    __shared__ int   s_ci[8][CAPW];
    __shared__ float s64v[64];
    __shared__ int   s64i[64];       // global idx = e*Vn + v
    __shared__ int   s_voc[8];
    __shared__ int   s_beam[8];
    __shared__ int   s_outs[Ln][En]; // 4 KB: outs[:, b, :]

    // Prefetch this thread's history element (tid -> (l = tid>>3, e = tid&7)).
    // Load issues NOW; the dependent LDS write is placed after the stream
    // loop, so the HBM latency hides under ~52 us of streaming.
    const int pf_l = tid >> 3;
    const int pf_e = tid & 7;
    const int my_out = outs[pf_l * BEn + b * 8 + pf_e];

    if (tid < 8) s_cnt[tid] = 0;
    __syncthreads();

    // --- Phase 1: stream. Wave w: segment e = w>>1, chunks [cstart, cend). ---
    {
        const int e  = w >> 1;
        const int h  = w & 1;
        const int be = b * 8 + e;
        if (ended[be] == 0) {
            const int cstart = h ? CHALF : 0;
            const int cend   = h ? NCH   : CHALF;
            const float4* row4 = (const float4*)(cp + (size_t)be * Vn);

            auto app = [&](float x, int v) {
                int p = atomicAdd(&s_cnt[e], 1);
                if (p < CAPW) { s_cv[e][p] = x; s_ci[e][p] = v; }
            };
            auto check4 = [&](float4 f, int strip) {
                float m = fmaxf(fmaxf(f.x, f.y), fmaxf(f.z, f.w));
                if (m > THRESH) {
                    int v0 = strip * 4;
                    if (f.x > THRESH) app(f.x, v0);
                    if (f.y > THRESH) app(f.y, v0 + 1);
                    if (f.z > THRESH) app(f.z, v0 + 2);
                    if (f.w > THRESH) app(f.w, v0 + 3);
                }
            };

            int c0 = cstart;
#pragma unroll 1
            for (; c0 + 8 <= cend; c0 += 8) {
                float4 f0 = ld_sel(row4 + (c0 + 0) * 64 + lane, true);
                float4 f1 = ld_sel(row4 + (c0 + 1) * 64 + lane, true);
                float4 f2 = ld_sel(row4 + (c0 + 2) * 64 + lane, true);
                float4 f3 = ld_sel(row4 + (c0 + 3) * 64 + lane, true);
                float4 f4 = ld_sel(row4 + (c0 + 4) * 64 + lane, true);
                float4 f5 = ld_sel(row4 + (c0 + 5) * 64 + lane, true);
                float4 f6 = ld_sel(row4 + (c0 + 6) * 64 + lane, true);
                float4 f7 = ld_sel(row4 + (c0 + 7) * 64 + lane, false);  // nt: 1/8
                check4(f0, (c0 + 0) * 64 + lane);
                check4(f1, (c0 + 1) * 64 + lane);
                check4(f2, (c0 + 2) * 64 + lane);
                check4(f3, (c0 + 3) * 64 + lane);
                check4(f4, (c0 + 4) * 64 + lane);
                check4(f5, (c0 + 5) * 64 + lane);
                check4(f6, (c0 + 6) * 64 + lane);
                check4(f7, (c0 + 7) * 64 + lane);
            }
            // Tail (<=7 chunks), issue all loads then consume.
            {
                float4 tf[7];
                int n = cend - c0;
#pragma unroll
                for (int k = 0; k < 7; ++k)
                    if (k < n) tf[k] = ld_sel(row4 + (c0 + k) * 64 + lane, true);
#pragma unroll
                for (int k = 0; k < 7; ++k)
                    if (k < n) check4(tf[k], (c0 + k) * 64 + lane);
            }
        }
    }
    // Park the prefetched history element (waitcnt for my_out lands here).
    s_outs[pf_l][pf_e] = my_out;
    __syncthreads();   // survivor lists + counts + history visible block-wide

    // --- Phase 2: per-segment exact top-8 (waves 0..7, wave w = segment w) ---
    if (w < 8) {
        const int e  = w;
        const int be = b * 8 + e;
        const float pr = proba[be];

        if (ended[be] != 0) {
            // Ended beam: (pr+0, END_TOK) then -inf at the 7 lowest indices.
            if (lane < 8) {
                if (lane == 0) { s64v[e * 8] = pr + 0.0f; s64i[e * 8] = e * Vn + END_TOK; }
                else {
                    int vloc = (lane - 1) + ((lane - 1) >= 2 ? 1 : 0);  // 0,1,3,4,5,6,7
                    s64v[e * 8 + lane] = NEG_INF;
                    s64i[e * 8 + lane] = e * Vn + vloc;
                }
            }
        } else {
            const int cnt = s_cnt[e];   // wave-uniform
            if (cnt >= 8 && cnt <= CAPW) {
                // Fast path: exact top-8 of <=128 survivors by (pr+v desc, idx asc).
                float bv0 = (lane      < cnt) ? pr + s_cv[e][lane]      : NEG_INF;
                int   bi0 = (lane      < cnt) ? s_ci[e][lane]           : IDX_SENTINEL;
                float bv1 = (lane + 64 < cnt) ? pr + s_cv[e][lane + 64] : NEG_INF;
                int   bi1 = (lane + 64 < cnt) ? s_ci[e][lane + 64]      : IDX_SENTINEL;
#pragma unroll
                for (int r = 0; r < 8; ++r) {
                    bool s0 = (bv0 > bv1) || (bv0 == bv1 && bi0 < bi1);
                    float lv = s0 ? bv0 : bv1;
                    int   li = s0 ? bi0 : bi1;
                    int   ll = lane;
                    wave_argmax(lv, li, ll);
                    if (ll == lane) {
                        if (bi0 == li && bv0 == lv) { bv0 = NEG_INF; bi0 = IDX_SENTINEL; }
                        else if (bi1 == li && bv1 == lv) { bv1 = NEG_INF; bi1 = IDX_SENTINEL; }
                    }
                    if (lane == r) { s64v[e * 8 + r] = lv; s64i[e * 8 + r] = e * Vn + li; }
                }
            } else {
                // Exact fallback (any input; ~never taken): per-lane top-8 rescan.
                const float4* row4 = (const float4*)(cp + (size_t)be * Vn);
                float bv[8]; int bi[8];
#pragma unroll
                for (int k = 0; k < 8; ++k) { bv[k] = NEG_INF; bi[k] = IDX_SENTINEL; }
                float mn = NEG_INF; int mi = IDX_SENTINEL;
                auto proc = [&](float val, int v) {
                    if (val > mn) {
                        bool done = false;
#pragma unroll
                        for (int k = 0; k < 8; ++k) {
                            bool m = !done && (bv[k] == mn) && (bi[k] == mi);
                            if (m) { bv[k] = val; bi[k] = v; }
                            done = done || m;
                        }
                        mn = bv[0]; mi = bi[0];
#pragma unroll
                        for (int k = 1; k < 8; ++k) {
                            bool t = (bv[k] < mn) || (bv[k] == mn && bi[k] > mi);
                            mn = t ? bv[k] : mn;
                            mi = t ? bi[k] : mi;
                        }
                    }
                };
                for (int q = lane; q < NV4; q += 64) {
                    float4 f = row4[q];
                    int v0 = q * 4;
                    proc(pr + f.x, v0);
                    proc(pr + f.y, v0 + 1);
                    proc(pr + f.z, v0 + 2);
                    proc(pr + f.w, v0 + 3);
                }
#pragma unroll
                for (int r = 0; r < 8; ++r) {
                    float lv = bv[0]; int li = bi[0];
#pragma unroll
                    for (int k = 1; k < 8; ++k) {
                        bool t = (bv[k] > lv) || (bv[k] == lv && bi[k] < li);
                        lv = t ? bv[k] : lv;
                        li = t ? bi[k] : li;
                    }
                    int ll = lane;
                    wave_argmax(lv, li, ll);
                    if (ll == lane) {
                        bool done = false;
#pragma unroll
                        for (int k = 0; k < 8; ++k) {
                            bool m = !done && (bi[k] == li) && (bv[k] == lv);
                            if (m) { bv[k] = NEG_INF; bi[k] = IDX_SENTINEL; }
                            done = done || m;
                        }
                    }
                    if (lane == r) { s64v[e * 8 + r] = lv; s64i[e * 8 + r] = e * Vn + li; }
                }
            }
        }
    }
    __syncthreads();   // all 64 block candidates ready

    // --- Phase 3: block merge (wave 0), scalar outputs ---
    if (w == 0) {
        float cv = s64v[lane];
        int   ci = s64i[lane];
#pragma unroll
        for (int r = 0; r < 8; ++r) {
            float lv = cv; int li = ci; int ll = lane;
            wave_argmax(lv, li, ll);
            if (ll == lane) { cv = NEG_INF; ci = IDX_SENTINEL; }
            if (lane == r) {
                unsigned u = (unsigned)li;
                int voc  = (int)(u % Vn);
                int beam = (int)(u / Vn);
                s_voc[r]  = voc;
                s_beam[r] = beam;
                dout[OFF_CUR  + b * 8 + r] = (float)voc;
                dout[OFF_TOPP + b * 8 + r] = lv;
                int endg = ended[b * 8 + beam];
                dout[OFF_ENDED + b * 8 + r] = (endg != 0 || voc == END_TOK) ? 1.0f : 0.0f;
                dout[OFF_BEAM  + b * 8 + r] = (float)beam;
            }
        }
    }
    __syncthreads();

    // --- Phase 4: gather history from LDS (no global round-trip) ---
    {
        const int bm = s_beam[pf_e];
        dout[OFF_OUTS + pf_l * BEn + b * 8 + pf_e] = (float)s_outs[pf_l][bm];
        if (tid < 8) dout[OFF_OUTS + Ln * BEn + b * 8 + tid] = (float)s_voc[tid];
    }
}

extern "C" void kernel_launch(void* const* d_in, const int* in_sizes, int n_in,
                              void* d_out, int out_size, void* d_ws, size_t ws_size,
                              hipStream_t stream) {
    const float* cp    = (const float*)d_in[0];  // [B*E, 1, V] fp32
    const float* proba = (const float*)d_in[1];  // [B, E] fp32
    const int*   outs  = (const int*)d_in[2];    // [L, B, E] int
    const int*   ended = (const int*)d_in[3];    // [B, E] bool->int
    float* dout = (float*)d_out;

    k_beam_add<<<Bn, 1024, 0, stream>>>(cp, proba, ended, outs, dout);
}

// Round 18
// 55.466 us; speedup vs baseline: 1.0142x; 1.0142x over previous
//
#include <hip/hip_runtime.h>

// Problem constants (from reference setup_inputs)
#define Bn 256
#define En 8
#define Vn 32000
#define Ln 128
#define BEn (Bn * En)        // 2048
#define END_TOK 2
#define NV4 (Vn / 4)         // 8000 float4 strips per segment
#define NCH 125              // 1KB chunks per segment (64 strips each)
#define CHALF 63             // first-half chunk count (h=0: [0,63), h=1: [63,125))
#define CAPW 128             // survivor-list capacity per segment (mean 43, sd 6.6)

// d_out layout (all values stored as float32, outputs concatenated in return order)
#define OFF_CUR   0                          // cur_input  [B*E]
#define OFF_TOPP  (BEn)                      // top_p      [B,E]
#define OFF_OUTS  (2 * BEn)                  // outs_new   [L+1,B,E]
#define OFF_ENDED (2 * BEn + (Ln + 1) * BEn) // ended_new  [B,E]
#define OFF_BEAM  (3 * BEn + (Ln + 1) * BEn) // topk_beam  [B,E]

#define NEG_INF (-__builtin_inff())
#define IDX_SENTINEL 0x7fffffff

// Filter threshold on RAW cp values (pr segment-constant + fp-add monotone
// => raw-order filter selects exactly the sum-order top-8 candidates).
// 8th order stat of 32000 N(0,1) ~ 3.55; P(count<8 | t=3.0) ~ 1e-9;
// P(count>128) ~ 1e-25. Both fall back to an exact rescan.
#define THRESH 3.0f

typedef __attribute__((ext_vector_type(4))) float f32x4;

__device__ __forceinline__ float4 ld_sel(const float4* p, bool prot) {
    if (prot) return *p;
    f32x4 t = __builtin_nontemporal_load((const f32x4*)p);
    union { f32x4 a; float4 b; } u; u.a = t; return u.b;
}

// Butterfly arg-max over 64 lanes under total order (val desc, idx asc).
__device__ __forceinline__ void wave_argmax(float& v, int& ix, int& ln) {
#pragma unroll
    for (int off = 32; off > 0; off >>= 1) {
        float v2 = __shfl_xor(v, off, 64);
        int   i2 = __shfl_xor(ix, off, 64);
        int   l2 = __shfl_xor(ln, off, 64);
        bool take = (v2 > v) || (v2 == v && i2 < ix);
        v  = take ? v2 : v;
        ix = take ? i2 : ix;
        ln = take ? l2 : ln;
    }
}

// Single fused kernel: one block per b, 16 waves (1024 threads).
// Wave w streams half (w&1) of segment w>>1 — a 63-64 KB sequential stream
// per wave, 16 streams/CU (measured optimum: 5.04 TB/s delivered read;
// same as 8x128KB, better than 4x256KB / 32-wave interleaved / LDS-DMA).
// Survivors go to per-segment LDS lists (two waves share one list via LDS
// atomics; final top-8 is set-determined so outputs stay deterministic).
// Waves 0..7 then select their segment's exact top-8; block merges 64 -> 8
// in reference order; scalars + history gather.
__global__ __launch_bounds__(1024) void k_beam_add(
        const float* __restrict__ cp, const float* __restrict__ proba,
        const int* __restrict__ ended, const int* __restrict__ outs,
        float* __restrict__ dout) {
    const int b    = blockIdx.x;
    const int tid  = threadIdx.x;
    const int w    = tid >> 6;       // wave 0..15
    const int lane = tid & 63;

    __shared__ int   s_cnt[8];
    __shared__ float s_cv[8][CAPW];
    __shared__ int   s_ci[8][CAPW];
    __shared__ float s64v[64];
    __shared__ int   s64i[64];       // global idx = e*Vn + v
    __shared__ int   s_voc[8];
    __shared__ int   s_beam[8];

    if (tid < 8) s_cnt[tid] = 0;
    __syncthreads();

    // --- Phase 1: stream. Wave w: segment e = w>>1, chunks [cstart, cend). ---
    {
        const int e  = w >> 1;
        const int h  = w & 1;
        const int be = b * 8 + e;
        if (ended[be] == 0) {
            const int cstart = h ? CHALF : 0;
            const int cend   = h ? NCH   : CHALF;
            const float4* row4 = (const float4*)(cp + (size_t)be * Vn);

            auto app = [&](float x, int v) {
                int p = atomicAdd(&s_cnt[e], 1);
                if (p < CAPW) { s_cv[e][p] = x; s_ci[e][p] = v; }
            };
            auto check4 = [&](float4 f, int strip) {
                float m = fmaxf(fmaxf(f.x, f.y), fmaxf(f.z, f.w));
                if (m > THRESH) {
                    int v0 = strip * 4;
                    if (f.x > THRESH) app(f.x, v0);
                    if (f.y > THRESH) app(f.y, v0 + 1);
                    if (f.z > THRESH) app(f.z, v0 + 2);
                    if (f.w > THRESH) app(f.w, v0 + 3);
                }
            };

            int c0 = cstart;
#pragma unroll 1
            for (; c0 + 8 <= cend; c0 += 8) {
                float4 f0 = ld_sel(row4 + (c0 + 0) * 64 + lane, true);
                float4 f1 = ld_sel(row4 + (c0 + 1) * 64 + lane, true);
                float4 f2 = ld_sel(row4 + (c0 + 2) * 64 + lane, true);
                float4 f3 = ld_sel(row4 + (c0 + 3) * 64 + lane, true);
                float4 f4 = ld_sel(row4 + (c0 + 4) * 64 + lane, true);
                float4 f5 = ld_sel(row4 + (c0 + 5) * 64 + lane, true);
                float4 f6 = ld_sel(row4 + (c0 + 6) * 64 + lane, true);
                float4 f7 = ld_sel(row4 + (c0 + 7) * 64 + lane, false);  // nt: 1/8
                check4(f0, (c0 + 0) * 64 + lane);
                check4(f1, (c0 + 1) * 64 + lane);
                check4(f2, (c0 + 2) * 64 + lane);
                check4(f3, (c0 + 3) * 64 + lane);
                check4(f4, (c0 + 4) * 64 + lane);
                check4(f5, (c0 + 5) * 64 + lane);
                check4(f6, (c0 + 6) * 64 + lane);
                check4(f7, (c0 + 7) * 64 + lane);
            }
            // Tail (<=7 chunks), issue all loads then consume.
            {
                float4 tf[7];
                int n = cend - c0;
#pragma unroll
                for (int k = 0; k < 7; ++k)
                    if (k < n) tf[k] = ld_sel(row4 + (c0 + k) * 64 + lane, true);
#pragma unroll
                for (int k = 0; k < 7; ++k)
                    if (k < n) check4(tf[k], (c0 + k) * 64 + lane);
            }
        }
    }
    __syncthreads();   // survivor lists + counts visible block-wide

    // --- Phase 2: per-segment exact top-8 (waves 0..7, wave w = segment w) ---
    if (w < 8) {
        const int e  = w;
        const int be = b * 8 + e;
        const float pr = proba[be];

        if (ended[be] != 0) {
            // Ended beam: (pr+0, END_TOK) then -inf at the 7 lowest indices.
            if (lane < 8) {
                if (lane == 0) { s64v[e * 8] = pr + 0.0f; s64i[e * 8] = e * Vn + END_TOK; }
                else {
                    int vloc = (lane - 1) + ((lane - 1) >= 2 ? 1 : 0);  // 0,1,3,4,5,6,7
                    s64v[e * 8 + lane] = NEG_INF;
                    s64i[e * 8 + lane] = e * Vn + vloc;
                }
            }
        } else {
            const int cnt = s_cnt[e];   // wave-uniform
            if (cnt >= 8 && cnt <= CAPW) {
                // Fast path: exact top-8 of <=128 survivors by (pr+v desc, idx asc).
                float bv0 = (lane      < cnt) ? pr + s_cv[e][lane]      : NEG_INF;
                int   bi0 = (lane      < cnt) ? s_ci[e][lane]           : IDX_SENTINEL;
                float bv1 = (lane + 64 < cnt) ? pr + s_cv[e][lane + 64] : NEG_INF;
                int   bi1 = (lane + 64 < cnt) ? s_ci[e][lane + 64]      : IDX_SENTINEL;
#pragma unroll
                for (int r = 0; r < 8; ++r) {
                    bool s0 = (bv0 > bv1) || (bv0 == bv1 && bi0 < bi1);
                    float lv = s0 ? bv0 : bv1;
                    int   li = s0 ? bi0 : bi1;
                    int   ll = lane;
                    wave_argmax(lv, li, ll);
                    if (ll == lane) {
                        if (bi0 == li && bv0 == lv) { bv0 = NEG_INF; bi0 = IDX_SENTINEL; }
                        else if (bi1 == li && bv1 == lv) { bv1 = NEG_INF; bi1 = IDX_SENTINEL; }
                    }
                    if (lane == r) { s64v[e * 8 + r] = lv; s64i[e * 8 + r] = e * Vn + li; }
                }
            } else {
                // Exact fallback (any input; ~never taken): per-lane top-8 rescan.
                const float4* row4 = (const float4*)(cp + (size_t)be * Vn);
                float bv[8]; int bi[8];
#pragma unroll
                for (int k = 0; k < 8; ++k) { bv[k] = NEG_INF; bi[k] = IDX_SENTINEL; }
                float mn = NEG_INF; int mi = IDX_SENTINEL;
                auto proc = [&](float val, int v) {
                    if (val > mn) {
                        bool done = false;
#pragma unroll
                        for (int k = 0; k < 8; ++k) {
                            bool m = !done && (bv[k] == mn) && (bi[k] == mi);
                            if (m) { bv[k] = val; bi[k] = v; }
                            done = done || m;
                        }
                        mn = bv[0]; mi = bi[0];
#pragma unroll
                        for (int k = 1; k < 8; ++k) {
                            bool t = (bv[k] < mn) || (bv[k] == mn && bi[k] > mi);
                            mn = t ? bv[k] : mn;
                            mi = t ? bi[k] : mi;
                        }
                    }
                };
                for (int q = lane; q < NV4; q += 64) {
                    float4 f = row4[q];
                    int v0 = q * 4;
                    proc(pr + f.x, v0);
                    proc(pr + f.y, v0 + 1);
                    proc(pr + f.z, v0 + 2);
                    proc(pr + f.w, v0 + 3);
                }
#pragma unroll
                for (int r = 0; r < 8; ++r) {
                    float lv = bv[0]; int li = bi[0];
#pragma unroll
                    for (int k = 1; k < 8; ++k) {
                        bool t = (bv[k] > lv) || (bv[k] == lv && bi[k] < li);
                        lv = t ? bv[k] : lv;
                        li = t ? bi[k] : li;
                    }
                    int ll = lane;
                    wave_argmax(lv, li, ll);
                    if (ll == lane) {
                        bool done = false;
#pragma unroll
                        for (int k = 0; k < 8; ++k) {
                            bool m = !done && (bi[k] == li) && (bv[k] == lv);
                            if (m) { bv[k] = NEG_INF; bi[k] = IDX_SENTINEL; }
                            done = done || m;
                        }
                    }
                    if (lane == r) { s64v[e * 8 + r] = lv; s64i[e * 8 + r] = e * Vn + li; }
                }
            }
        }
    }
    __syncthreads();   // all 64 block candidates ready

    // --- Phase 3: block merge (wave 0), scalar outputs ---
    if (w == 0) {
        float cv = s64v[lane];
        int   ci = s64i[lane];
#pragma unroll
        for (int r = 0; r < 8; ++r) {
            float lv = cv; int li = ci; int ll = lane;
            wave_argmax(lv, li, ll);
            if (ll == lane) { cv = NEG_INF; ci = IDX_SENTINEL; }
            if (lane == r) {
                unsigned u = (unsigned)li;
                int voc  = (int)(u % Vn);
                int beam = (int)(u / Vn);
                s_voc[r]  = voc;
                s_beam[r] = beam;
                dout[OFF_CUR  + b * 8 + r] = (float)voc;
                dout[OFF_TOPP + b * 8 + r] = lv;
                int endg = ended[b * 8 + beam];
                dout[OFF_ENDED + b * 8 + r] = (endg != 0 || voc == END_TOK) ? 1.0f : 0.0f;
                dout[OFF_BEAM  + b * 8 + r] = (float)beam;
            }
        }
    }
    __syncthreads();

    // --- Phase 4: gather history. Ln*En = 1024 = 1 per thread + last row ---
    {
        const int e0   = tid & 7;
        const int l0   = tid >> 3;               // 0..127
        const int bm   = s_beam[e0];
        const int base = b * 8;
        int g0 = outs[l0 * BEn + base + bm];
        dout[OFF_OUTS + l0 * BEn + base + e0] = (float)g0;
        if (tid < 8) dout[OFF_OUTS + Ln * BEn + base + tid] = (float)s_voc[tid];
    }
}

extern "C" void kernel_launch(void* const* d_in, const int* in_sizes, int n_in,
                              void* d_out, int out_size, void* d_ws, size_t ws_size,
                              hipStream_t stream) {
    const float* cp    = (const float*)d_in[0];  // [B*E, 1, V] fp32
    const float* proba = (const float*)d_in[1];  // [B, E] fp32
    const int*   outs  = (const int*)d_in[2];    // [L, B, E] int
    const int*   ended = (const int*)d_in[3];    // [B, E] bool->int
    float* dout = (float*)d_out;

    k_beam_add<<<Bn, 1024, 0, stream>>>(cp, proba, ended, outs, dout);
}